// Round 7
// baseline (202.002 us; speedup 1.0000x reference)
//
#include <hip/hip_runtime.h>
#include <math.h>

#define B_    4
#define C_    19
#define H_    320
#define W_    320
#define HW_   (H_*W_)
#define CHW_  (C_*HW_)
#define NPIX_ (B_*HW_)
#define NEPS_ 256
#define BIGI_ (1<<20)
#define INF_  0x3fffffff
#define IGN_  255

// Compile-time exact replica of the reference eps chain: e0=1e-5f, e_{k+1}=e_k*1.2f
struct EpsTab { float v[NEPS_]; };
static constexpr EpsTab make_eps() {
  EpsTab t{}; float e = 1e-5f;
  for (int k = 0; k < NEPS_; ++k) { t.v[k] = e; e = e * 1.2f; }
  return t;
}
__device__ __constant__ EpsTab EPS = make_eps();

// ---------------- reduction helper (nw full waves) ---------------------------
__device__ __forceinline__ void block_reduce_add_w(float v, float* out, int nw) {
  #pragma unroll
  for (int o = 32; o > 0; o >>= 1) v += __shfl_down(v, o);
  __shared__ float shr[8];
  int lane = threadIdx.x & 63, wid = threadIdx.x >> 6;
  if (lane == 0) shr[wid] = v;
  __syncthreads();
  if (threadIdx.x == 0) {
    float s = 0.f;
    for (int w = 0; w < nw; ++w) s += shr[w];
    atomicAdd(out, s);
  }
}

__device__ __forceinline__ int eps_bin(float kl, const float* et) {
  // #{k : e_k < kl}, log2 guess + exact correction (identical compares to ref)
  if (!(kl > 1e-5f)) return 0;
  int g = (int)((__log2f(kl) + 16.6096404f) * 3.8017840f);
  g = min(max(g, 0), NEPS_ - 1);
  while (g < NEPS_ && et[g] < kl) ++g;
  while (g > 0 && !(et[g - 1] < kl)) --g;
  return g;
}

// ---------------- K1: row distance transform + workspace init ---------------
__global__ __launch_bounds__(320) void k_rowdt(const int* __restrict__ tgt, int* __restrict__ Rt,
                                               int* __restrict__ hist, float* __restrict__ out) {
  int bid = blockIdx.x;                  // b*H_ + i
  int b = bid / H_, i = bid - b * H_;
  int j = threadIdx.x, lane = j & 63, wv = j >> 6;
  if (bid == 0) {
    if (j < 257) hist[j] = 0;
    if (j == 319) out[0] = 0.f;
  }
  bool hd = (i < H_ - 1);
  const int* trow = tgt + b * HW_ + i * W_;
  int t0 = trow[j];
  int t1 = hd ? trow[W_ + j] : t0;
  int t0r = (j < W_ - 1) ? trow[j + 1] : t0;
  bool bnd = (t0 == IGN_) || (t1 != t0) || (t0r != t0);
  int s = bnd ? 0 : BIGI_;
  int a = s - j, c = s + j;
  #pragma unroll
  for (int o = 1; o < 64; o <<= 1) {
    int v = __shfl_up(a, o);
    if (lane >= o) a = min(a, v);
    int w = __shfl_down(c, o);
    if (lane + o < 64) c = min(c, w);
  }
  __shared__ int wa[5], wc[5];
  if (lane == 63) wa[wv] = a;
  if (lane == 0)  wc[wv] = c;
  __syncthreads();
  #pragma unroll
  for (int w = 0; w < 5; ++w) {
    if (w < wv) a = min(a, wa[w]);
    if (w > wv) c = min(c, wc[w]);
  }
  Rt[(b * W_ + j) * H_ + i] = min(a + j, c - j);   // transposed store
}

// ---------------- K0: per-PAIR softmax/KL (float2 + shfl-right) -------------
// Round-4 float2 kernel with the right-neighbor global stream eliminated:
//  * xr_c = __shfl_down(xo.x, 1)  (thread t+1 owns pixel p+2's logits)
//  * right-pixel logZ = __shfl_down(lz0, 1) -- bit-copy of the float the
//    neighbor thread computed itself (identical accumulation), so bitwise
//    unchanged vs rounds 1-6 (absmax 0.0 throughout).
//  * wave boundary: lane-0 threads publish their 19 x values + lz to LDS;
//    lane 63 of wave w reads xb/lzw[w+1]. tid 255 (block boundary) alone
//    keeps the exec-masked scalar-load + exp path.
// Removes 19 of 57 load instrs, 19 of 95 exps, and a 19-deep serial add
// chain per 2 pixels.
__global__ __launch_bounds__(256) void k_soft(const float* __restrict__ sl, const int* __restrict__ tgt,
                                              float* __restrict__ logZ, float* __restrict__ S,
                                              float* __restrict__ kl_map, int* __restrict__ hist,
                                              float* __restrict__ out) {
  int t = blockIdx.x * 256 + threadIdx.x;        // pair index, 0..NPIX_/2-1
  int b = t / (HW_ / 2), q = t - b * (HW_ / 2);
  int p = q * 2;                                 // pixel base (j even)
  int i = p / W_, j = p - i * W_;
  int lane = threadIdx.x & 63, wv = threadIdx.x >> 6;
  bool hd = (i < H_ - 1);
  bool hr1 = (j + 2 < W_);                       // pixel1 has a right neighbor
  bool e63 = (lane == 63);
  __shared__ float et[NEPS_];
  __shared__ int sh[257];
  __shared__ float xb[4][C_];                    // wave-head own logits
  __shared__ float lzw[4];                       // wave-head own logZ
  et[threadIdx.x] = EPS.v[threadIdx.x];
  sh[threadIdx.x] = 0;
  if (threadIdx.x == 0) sh[256] = 0;

  const float* base = sl + (size_t)b * CHW_ + p;
  int2 t2 = *(const int2*)(tgt + b * HW_ + p);
  // pre-pass: lane-0 threads publish their per-channel x (their own xo.x)
  if (lane == 0) {
    #pragma unroll
    for (int c = 0; c < C_; ++c) xb[wv][c] = base[c * HW_];
  }
  __syncthreads();                               // et, sh, xb visible

  float se0=0.f,se1=0.f, E0=0.f,E1=0.f;
  float dD0=0.f,dD1=0.f, sB0=0.f,sB1=0.f;
  float dR0=0.f,dR1=0.f;
  float xt0=0.f,xt1=0.f, seE=0.f;
  #pragma unroll
  for (int c = 0; c < C_; ++c) {
    const float* pc = base + c * HW_;
    float2 xo = *(const float2*)pc;
    float2 xd = hd ? *(const float2*)(pc + W_) : make_float2(0.f, 0.f);
    float xr = __shfl_down(xo.x, 1);             // pixel p+2's logit (lane<63)
    if (e63) {
      xr = (wv < 3) ? xb[wv + 1][c] : (hr1 ? pc[2] : 0.f);
      seE += __expf(xr);                         // only used by tid 255
    }
    float e0 = __expf(xo.x), e1 = __expf(xo.y);
    se0 += e0; E0 += e0 * xo.x;
    se1 += e1; E1 += e1 * xo.y;
    dD0 += e0 * xd.x; dD1 += e1 * xd.y;
    sB0 += __expf(xd.x); sB1 += __expf(xd.y);
    dR0 += e0 * xo.y;                            // pixel0's right = pixel1 (in-reg)
    dR1 += e1 * xr;
    if (c == t2.x) xt0 = xo.x;
    if (c == t2.y) xt1 = xo.y;
  }
  float lz0 = __logf(se0), lz1 = __logf(se1);
  float Sv0 = E0 / se0 - lz0, Sv1 = E1 / se1 - lz1;
  float nll = ((t2.x != IGN_) ? (lz0 - xt0) : 0.f) + ((t2.y != IGN_) ? (lz1 - xt1) : 0.f);
  // kl_tb (0 at last row)
  float kl0 = hd ? (Sv0 - dD0 / se0 + __logf(sB0)) : 0.f;
  float kl1 = hd ? (Sv1 - dD1 / se1 + __logf(sB1)) : 0.f;
  // kl_lr pixel0: right neighbor is pixel1 (register stats, bitwise = its own)
  kl0 += Sv0 - dR0 / se0 + lz1;
  if (lane == 0) lzw[wv] = lz0;
  __syncthreads();                               // lzw visible (et/sh already)
  // kl_lr pixel1: right-pixel logZ via shfl / wave patch / edge recompute
  float lzr1 = __shfl_down(lz0, 1);
  if (e63) lzr1 = (wv < 3) ? lzw[wv + 1] : __logf(seE);
  if (hr1) kl1 += Sv1 - dR1 / se1 + lzr1;
  int gp = b * HW_ + p;
  *(float2*)(logZ + gp)   = make_float2(lz0, lz1);
  *(float2*)(S + gp)      = make_float2(Sv0, Sv1);
  *(float2*)(kl_map + gp) = make_float2(kl0, kl1);
  atomicAdd(&sh[eps_bin(kl0, et)], 1);
  atomicAdd(&sh[eps_bin(kl1, et)], 1);
  __syncthreads();
  if (sh[threadIdx.x]) atomicAdd(&hist[threadIdx.x], sh[threadIdx.x]);
  if (threadIdx.x == 0 && sh[256]) atomicAdd(&hist[256], sh[256]);
  block_reduce_add_w(nll, out, 4);
}

// ---------------- K2: column combine + (block 0) eps selection --------------
__global__ __launch_bounds__(H_) void k_coldt(const int* __restrict__ Rt, int* __restrict__ dist,
                                              const int* __restrict__ hist, float* __restrict__ eps_sel) {
  int b = blockIdx.x / W_, j = blockIdx.x % W_, tid = threadIdx.x;
  __shared__ int lev[9][H_];
  lev[0][tid] = Rt[(b * W_ + j) * H_ + tid];
  int Ri = lev[0][tid];
  for (int l = 1; l <= 8; ++l) {
    int half = 1 << (l - 1);
    __syncthreads();
    int other = (tid + half < H_) ? lev[l - 1][tid + half] : INF_;
    lev[l][tid] = min(lev[l - 1][tid], other);
  }
  __syncthreads();
  int i0 = tid;
  auto feas = [&](int dd) -> bool {
    int lo = max(0, i0 - dd), hi = min(H_ - 1, i0 + dd);
    int len = hi - lo + 1;
    int l = 31 - __clz(len);
    int m = min(lev[l][lo], lev[l][hi - (1 << l) + 1]);
    return m <= dd;
  };
  int d;
  int hi = min(Ri, 512);                 // d <= R[i0]
  if (!feas(hi)) d = B_ + 1 + H_ + W_;   // no seed in image
  else {
    int lo = 0;
    while (lo < hi) { int mid = (lo + hi) >> 1; if (feas(mid)) hi = mid; else lo = mid + 1; }
    d = lo;
  }
  dist[(b * H_ + i0) * W_ + j] = d;
  // block 0: eps via suffix scan of hist (bins 1..256)
  if (blockIdx.x == 0) {
    __shared__ int g[256];
    __shared__ int bestk;
    if (tid < 256) g[tid] = hist[tid + 1];
    if (tid == 0) bestk = NEPS_ - 1;
    __syncthreads();
    #pragma unroll
    for (int ofs = 1; ofs < 256; ofs <<= 1) {
      int v = 0;
      if (tid < 256) v = g[tid] + ((tid + ofs < 256) ? g[tid + ofs] : 0);
      __syncthreads();
      if (tid < 256) g[tid] = v;
      __syncthreads();
    }
    if (tid < 256 && g[tid] <= 5120) atomicMin(&bestk, tid);
    __syncthreads();
    if (tid == 0) eps_sel[0] = EPS.v[bestk];
  }
}

// ---------------- K3: mask+direction+dterm + in-block sparse CE -------------
// 8x8 tiles (was 16x16): 6400 blocks = 25 blocks/CU (was 1.6) so the CE
// phase's scattered loads get enough concurrency to hide latency.
__global__ __launch_bounds__(256) void k_maskce(const float* __restrict__ sl, const float* __restrict__ logZ,
                                                const float* __restrict__ S, const float* __restrict__ kl_map,
                                                const int* __restrict__ dist, const float* __restrict__ eps_sel,
                                                float* __restrict__ out) {
  const int nx9[9] = {1,-1,0,0,-1,1,-1,1,0};
  const int ny9[9] = {0,0,-1,1,1,1,-1,-1,0};
  int tid = threadIdx.x;
  int b = blockIdx.z;
  int i0 = blockIdx.y * 8, j0 = blockIdx.x * 8;
  float eps = eps_sel[0];
  __shared__ float kt[10][11];
  __shared__ int   dt_[10][11];
  for (int e = tid; e < 100; e += 256) {
    int r = e / 10, cc = e - r * 10;
    int gi = i0 - 1 + r, gj = j0 - 1 + cc;
    bool in = (gi >= 0 && gi < H_ && gj >= 0 && gj < W_);
    int gidx = (b * H_ + gi) * W_ + gj;
    kt[r][cc]  = in ? kl_map[gidx] : -1e30f;
    dt_[r][cc] = in ? dist[gidx] : 100000;
  }
  __syncthreads();
  bool valid = false;
  int dir = 0;
  float acc = 0.f;
  if (tid < 64) {
    int li = tid >> 3, lj = tid & 7;
    bool mask = false;
    #pragma unroll
    for (int dr = 0; dr < 3; ++dr)
      #pragma unroll
      for (int dc = 0; dc < 3; ++dc)
        mask |= (kt[li + dr][lj + dc] > eps);
    int best = INF_;
    #pragma unroll
    for (int k = 0; k < 9; ++k) {
      int r = dt_[li + 1 + nx9[k]][lj + 1 + ny9[k]];
      if (r < best) { best = r; dir = k; }
    }
    valid = mask && (dir != 8);
    if (valid) acc = fminf((float)dt_[li + 1][lj + 1], 20.f) * (1.f / 20.f);
  }
  // compact valid pixels into LDS list (only wave 0 can be valid)
  __shared__ int list_[64];
  __shared__ int woff[4];
  __shared__ int tot_s;
  int lane = tid & 63, wid = tid >> 6;
  unsigned long long vote = __ballot(valid);
  if (lane == 0) woff[wid] = __popcll(vote);
  __syncthreads();
  if (tid == 0) {
    int c0 = woff[0], c1 = woff[1], c2 = woff[2], c3 = woff[3];
    tot_s = c0 + c1 + c2 + c3;
    woff[0] = 0; woff[1] = c0; woff[2] = c0 + c1; woff[3] = c0 + c1 + c2;
  }
  __syncthreads();
  if (valid)
    list_[woff[wid] + __popcll(vote & ((1ULL << lane) - 1ULL))] = tid | (min(dir, 7) << 8);
  __syncthreads();
  int cnt = tot_s;
  const float* bse = sl + (size_t)b * CHW_;
  // CE: 8 lanes per entry (lane k = neighbor k), 32 entries per pass
  for (int base0 = 0; base0 < cnt; base0 += 32) {
    int e = base0 + (tid >> 3), k = tid & 7;
    float ce = 0.f;
    if (e < cnt) {
      int w = list_[e];
      int label = w >> 8, lpos = w & 255;
      int i = i0 + (lpos >> 3), j = j0 + (lpos & 7);
      int pix = i * W_ + j;
      float lzc = logZ[b * HW_ + pix];
      int ic = min(max(i + nx9[k], 0), H_ - 1);
      int jc = min(max(j + ny9[k], 0), W_ - 1);
      int npx = ic * W_ + jc;
      float lzn = logZ[b * HW_ + npx], Sn = S[b * HW_ + npx];
      float dot = 0.f;
      #pragma unroll
      for (int c = 0; c < C_; ++c)
        dot += __expf(bse[c * HW_ + npx] - lzn) * bse[c * HW_ + pix];
      float kv = Sn - dot + lzc;
      float kmax = kv;
      #pragma unroll
      for (int o = 1; o < 8; o <<= 1) kmax = fmaxf(kmax, __shfl_xor(kmax, o));
      float ssum = __expf(kv - kmax);
      #pragma unroll
      for (int o = 1; o < 8; o <<= 1) ssum += __shfl_xor(ssum, o);
      float kll = __shfl(kv, (lane & ~7) | label);
      if (k == 0) ce = kmax + __logf(ssum) - kll;
    }
    acc += ce;
  }
  block_reduce_add_w(acc, out, 4);
}

// ---------------- launch -----------------------------------------------------
extern "C" void kernel_launch(void* const* d_in, const int* in_sizes, int n_in,
                              void* d_out, int out_size, void* d_ws, size_t ws_size,
                              hipStream_t stream) {
  const float* sl  = (const float*)d_in[0];
  const int*   tgt = (const int*)d_in[1];
  float* out = (float*)d_out;

  int*   hist    = (int*)d_ws;                 // 257 ints (zeroed by k_rowdt)
  float* eps_sel = (float*)d_ws + 320;
  float* logZ    = (float*)d_ws + 512;
  float* S       = logZ + NPIX_;
  float* kl_map  = S + NPIX_;
  int*   dist    = (int*)(kl_map + NPIX_);
  int*   Rt      = dist + NPIX_;

  k_rowdt<<<B_ * H_, W_, 0, stream>>>(tgt, Rt, hist, out);
  k_soft<<<NPIX_ / 2 / 256, 256, 0, stream>>>(sl, tgt, logZ, S, kl_map, hist, out);
  k_coldt<<<B_ * W_, H_, 0, stream>>>(Rt, dist, hist, eps_sel);
  k_maskce<<<dim3(W_ / 8, H_ / 8, B_), 256, 0, stream>>>(sl, logZ, S, kl_map, dist, eps_sel, out);
}

// Round 8
// 150.842 us; speedup vs baseline: 1.3392x; 1.3392x over previous
//
#include <hip/hip_runtime.h>
#include <math.h>

#define B_    4
#define C_    19
#define H_    320
#define W_    320
#define HW_   (H_*W_)
#define CHW_  (C_*HW_)
#define NPIX_ (B_*HW_)
#define NEPS_ 256
#define BIGI_ (1<<20)
#define INF_  0x3fffffff
#define IGN_  255

// Compile-time exact replica of the reference eps chain: e0=1e-5f, e_{k+1}=e_k*1.2f
struct EpsTab { float v[NEPS_]; };
static constexpr EpsTab make_eps() {
  EpsTab t{}; float e = 1e-5f;
  for (int k = 0; k < NEPS_; ++k) { t.v[k] = e; e = e * 1.2f; }
  return t;
}
__device__ __constant__ EpsTab EPS = make_eps();

// ---------------- reduction helper (nw full waves) ---------------------------
__device__ __forceinline__ void block_reduce_add_w(float v, float* out, int nw) {
  #pragma unroll
  for (int o = 32; o > 0; o >>= 1) v += __shfl_down(v, o);
  __shared__ float shr[8];
  int lane = threadIdx.x & 63, wid = threadIdx.x >> 6;
  if (lane == 0) shr[wid] = v;
  __syncthreads();
  if (threadIdx.x == 0) {
    float s = 0.f;
    for (int w = 0; w < nw; ++w) s += shr[w];
    atomicAdd(out, s);
  }
}

__device__ __forceinline__ int eps_bin(float kl, const float* et) {
  // #{k : e_k < kl}, log2 guess + exact correction (identical compares to ref)
  if (!(kl > 1e-5f)) return 0;
  int g = (int)((__log2f(kl) + 16.6096404f) * 3.8017840f);
  g = min(max(g, 0), NEPS_ - 1);
  while (g < NEPS_ && et[g] < kl) ++g;
  while (g > 0 && !(et[g - 1] < kl)) --g;
  return g;
}

// ---------------- K1: row distance transform + workspace init ---------------
__global__ __launch_bounds__(320) void k_rowdt(const int* __restrict__ tgt, int* __restrict__ Rt,
                                               int* __restrict__ hist, float* __restrict__ out) {
  int bid = blockIdx.x;                  // b*H_ + i
  int b = bid / H_, i = bid - b * H_;
  int j = threadIdx.x, lane = j & 63, wv = j >> 6;
  if (bid == 0) {
    if (j < 257) hist[j] = 0;
    if (j == 319) out[0] = 0.f;
  }
  bool hd = (i < H_ - 1);
  const int* trow = tgt + b * HW_ + i * W_;
  int t0 = trow[j];
  int t1 = hd ? trow[W_ + j] : t0;
  int t0r = (j < W_ - 1) ? trow[j + 1] : t0;
  bool bnd = (t0 == IGN_) || (t1 != t0) || (t0r != t0);
  int s = bnd ? 0 : BIGI_;
  int a = s - j, c = s + j;
  #pragma unroll
  for (int o = 1; o < 64; o <<= 1) {
    int v = __shfl_up(a, o);
    if (lane >= o) a = min(a, v);
    int w = __shfl_down(c, o);
    if (lane + o < 64) c = min(c, w);
  }
  __shared__ int wa[5], wc[5];
  if (lane == 63) wa[wv] = a;
  if (lane == 0)  wc[wv] = c;
  __syncthreads();
  #pragma unroll
  for (int w = 0; w < 5; ++w) {
    if (w < wv) a = min(a, wa[w]);
    if (w > wv) c = min(c, wc[w]);
  }
  Rt[(b * W_ + j) * H_ + i] = min(a + j, c - j);   // transposed store
}

// ---------------- K0: per-PAIR softmax/KL (float2 + shfl-right) -------------
// Measured-by-subtraction at ~14-16us in round 7 (vs ~30 for the 3-stream
// version). Right-neighbor logits via __shfl_down(xo.x,1); right-pixel logZ
// via __shfl_down(lz0,1) -- bit-copies of floats computed by the neighbor
// thread with identical accumulation (absmax 0.0, rounds 1-7). Wave-boundary
// lanes patched from LDS; tid-255 keeps the exec-masked scalar path.
__global__ __launch_bounds__(256) void k_soft(const float* __restrict__ sl, const int* __restrict__ tgt,
                                              float* __restrict__ logZ, float* __restrict__ S,
                                              float* __restrict__ kl_map, int* __restrict__ hist,
                                              float* __restrict__ out) {
  int t = blockIdx.x * 256 + threadIdx.x;        // pair index, 0..NPIX_/2-1
  int b = t / (HW_ / 2), q = t - b * (HW_ / 2);
  int p = q * 2;                                 // pixel base (j even)
  int i = p / W_, j = p - i * W_;
  int lane = threadIdx.x & 63, wv = threadIdx.x >> 6;
  bool hd = (i < H_ - 1);
  bool hr1 = (j + 2 < W_);                       // pixel1 has a right neighbor
  bool e63 = (lane == 63);
  __shared__ float et[NEPS_];
  __shared__ int sh[257];
  __shared__ float xb[4][C_];                    // wave-head own logits
  __shared__ float lzw[4];                       // wave-head own logZ
  et[threadIdx.x] = EPS.v[threadIdx.x];
  sh[threadIdx.x] = 0;
  if (threadIdx.x == 0) sh[256] = 0;

  const float* base = sl + (size_t)b * CHW_ + p;
  int2 t2 = *(const int2*)(tgt + b * HW_ + p);
  // pre-pass: lane-0 threads publish their per-channel x (their own xo.x)
  if (lane == 0) {
    #pragma unroll
    for (int c = 0; c < C_; ++c) xb[wv][c] = base[c * HW_];
  }
  __syncthreads();                               // et, sh, xb visible

  float se0=0.f,se1=0.f, E0=0.f,E1=0.f;
  float dD0=0.f,dD1=0.f, sB0=0.f,sB1=0.f;
  float dR0=0.f,dR1=0.f;
  float xt0=0.f,xt1=0.f, seE=0.f;
  #pragma unroll
  for (int c = 0; c < C_; ++c) {
    const float* pc = base + c * HW_;
    float2 xo = *(const float2*)pc;
    float2 xd = hd ? *(const float2*)(pc + W_) : make_float2(0.f, 0.f);
    float xr = __shfl_down(xo.x, 1);             // pixel p+2's logit (lane<63)
    if (e63) {
      xr = (wv < 3) ? xb[wv + 1][c] : (hr1 ? pc[2] : 0.f);
      seE += __expf(xr);                         // only used by tid 255
    }
    float e0 = __expf(xo.x), e1 = __expf(xo.y);
    se0 += e0; E0 += e0 * xo.x;
    se1 += e1; E1 += e1 * xo.y;
    dD0 += e0 * xd.x; dD1 += e1 * xd.y;
    sB0 += __expf(xd.x); sB1 += __expf(xd.y);
    dR0 += e0 * xo.y;                            // pixel0's right = pixel1 (in-reg)
    dR1 += e1 * xr;
    if (c == t2.x) xt0 = xo.x;
    if (c == t2.y) xt1 = xo.y;
  }
  float lz0 = __logf(se0), lz1 = __logf(se1);
  float Sv0 = E0 / se0 - lz0, Sv1 = E1 / se1 - lz1;
  float nll = ((t2.x != IGN_) ? (lz0 - xt0) : 0.f) + ((t2.y != IGN_) ? (lz1 - xt1) : 0.f);
  // kl_tb (0 at last row)
  float kl0 = hd ? (Sv0 - dD0 / se0 + __logf(sB0)) : 0.f;
  float kl1 = hd ? (Sv1 - dD1 / se1 + __logf(sB1)) : 0.f;
  // kl_lr pixel0: right neighbor is pixel1 (register stats, bitwise = its own)
  kl0 += Sv0 - dR0 / se0 + lz1;
  if (lane == 0) lzw[wv] = lz0;
  __syncthreads();                               // lzw visible (et/sh already)
  // kl_lr pixel1: right-pixel logZ via shfl / wave patch / edge recompute
  float lzr1 = __shfl_down(lz0, 1);
  if (e63) lzr1 = (wv < 3) ? lzw[wv + 1] : __logf(seE);
  if (hr1) kl1 += Sv1 - dR1 / se1 + lzr1;
  int gp = b * HW_ + p;
  *(float2*)(logZ + gp)   = make_float2(lz0, lz1);
  *(float2*)(S + gp)      = make_float2(Sv0, Sv1);
  *(float2*)(kl_map + gp) = make_float2(kl0, kl1);
  atomicAdd(&sh[eps_bin(kl0, et)], 1);
  atomicAdd(&sh[eps_bin(kl1, et)], 1);
  __syncthreads();
  if (sh[threadIdx.x]) atomicAdd(&hist[threadIdx.x], sh[threadIdx.x]);
  if (threadIdx.x == 0 && sh[256]) atomicAdd(&hist[256], sh[256]);
  block_reduce_add_w(nll, out, 4);
}

// ---------------- K2: column combine + (block 0) eps selection --------------
__global__ __launch_bounds__(H_) void k_coldt(const int* __restrict__ Rt, int* __restrict__ dist,
                                              const int* __restrict__ hist, float* __restrict__ eps_sel) {
  int b = blockIdx.x / W_, j = blockIdx.x % W_, tid = threadIdx.x;
  __shared__ int lev[9][H_];
  lev[0][tid] = Rt[(b * W_ + j) * H_ + tid];
  int Ri = lev[0][tid];
  for (int l = 1; l <= 8; ++l) {
    int half = 1 << (l - 1);
    __syncthreads();
    int other = (tid + half < H_) ? lev[l - 1][tid + half] : INF_;
    lev[l][tid] = min(lev[l - 1][tid], other);
  }
  __syncthreads();
  int i0 = tid;
  auto feas = [&](int dd) -> bool {
    int lo = max(0, i0 - dd), hi = min(H_ - 1, i0 + dd);
    int len = hi - lo + 1;
    int l = 31 - __clz(len);
    int m = min(lev[l][lo], lev[l][hi - (1 << l) + 1]);
    return m <= dd;
  };
  int d;
  int hi = min(Ri, 512);                 // d <= R[i0]
  if (!feas(hi)) d = B_ + 1 + H_ + W_;   // no seed in image
  else {
    int lo = 0;
    while (lo < hi) { int mid = (lo + hi) >> 1; if (feas(mid)) hi = mid; else lo = mid + 1; }
    d = lo;
  }
  dist[(b * H_ + i0) * W_ + j] = d;
  // block 0: eps via suffix scan of hist (bins 1..256)
  if (blockIdx.x == 0) {
    __shared__ int g[256];
    __shared__ int bestk;
    if (tid < 256) g[tid] = hist[tid + 1];
    if (tid == 0) bestk = NEPS_ - 1;
    __syncthreads();
    #pragma unroll
    for (int ofs = 1; ofs < 256; ofs <<= 1) {
      int v = 0;
      if (tid < 256) v = g[tid] + ((tid + ofs < 256) ? g[tid + ofs] : 0);
      __syncthreads();
      if (tid < 256) g[tid] = v;
      __syncthreads();
    }
    if (tid < 256 && g[tid] <= 5120) atomicMin(&bestk, tid);
    __syncthreads();
    if (tid == 0) eps_sel[0] = EPS.v[bestk];
  }
}

// ---------------- K3: mask+direction+dterm + in-block sparse CE -------------
// EXACT round-6 16x16 version (1600 blocks). Round 7 proved 8x8 tiles are a
// 6-7x regression: per-block fixed cost (halo round-trip, barriers, compact,
// idle CE lanes) dominates; the CE phase was never concurrency-starved.
__global__ __launch_bounds__(256) void k_maskce(const float* __restrict__ sl, const float* __restrict__ logZ,
                                                const float* __restrict__ S, const float* __restrict__ kl_map,
                                                const int* __restrict__ dist, const float* __restrict__ eps_sel,
                                                float* __restrict__ out) {
  const int nx9[9] = {1,-1,0,0,-1,1,-1,1,0};
  const int ny9[9] = {0,0,-1,1,1,1,-1,-1,0};
  int tid = threadIdx.x;
  int b = blockIdx.z;
  int i0 = blockIdx.y * 16, j0 = blockIdx.x * 16;
  float eps = eps_sel[0];
  __shared__ float kt[18][19];
  __shared__ int   dt_[18][19];
  for (int e = tid; e < 324; e += 256) {
    int r = e / 18, cc = e - r * 18;
    int gi = i0 - 1 + r, gj = j0 - 1 + cc;
    bool in = (gi >= 0 && gi < H_ && gj >= 0 && gj < W_);
    int gidx = (b * H_ + gi) * W_ + gj;
    kt[r][cc]  = in ? kl_map[gidx] : -1e30f;
    dt_[r][cc] = in ? dist[gidx] : 100000;
  }
  __syncthreads();
  int li = tid >> 4, lj = tid & 15;
  bool mask = false;
  #pragma unroll
  for (int dr = 0; dr < 3; ++dr)
    #pragma unroll
    for (int dc = 0; dc < 3; ++dc)
      mask |= (kt[li + dr][lj + dc] > eps);
  int best = INF_, dir = 0;
  #pragma unroll
  for (int k = 0; k < 9; ++k) {
    int r = dt_[li + 1 + nx9[k]][lj + 1 + ny9[k]];
    if (r < best) { best = r; dir = k; }
  }
  bool valid = mask && (dir != 8);
  float acc = valid ? fminf((float)dt_[li + 1][lj + 1], 20.f) * (1.f / 20.f) : 0.f;
  // compact valid pixels into LDS list
  __shared__ int list_[256];
  __shared__ int woff[4];
  __shared__ int tot_s;
  int lane = tid & 63, wid = tid >> 6;
  unsigned long long vote = __ballot(valid);
  if (lane == 0) woff[wid] = __popcll(vote);
  __syncthreads();
  if (tid == 0) {
    int c0 = woff[0], c1 = woff[1], c2 = woff[2], c3 = woff[3];
    tot_s = c0 + c1 + c2 + c3;
    woff[0] = 0; woff[1] = c0; woff[2] = c0 + c1; woff[3] = c0 + c1 + c2;
  }
  __syncthreads();
  if (valid)
    list_[woff[wid] + __popcll(vote & ((1ULL << lane) - 1ULL))] = tid | (min(dir, 7) << 8);
  __syncthreads();
  int cnt = tot_s;
  const float* bse = sl + (size_t)b * CHW_;
  // CE: 8 lanes per entry (lane k = neighbor k)
  for (int base0 = 0; base0 < cnt; base0 += 32) {
    int e = base0 + (tid >> 3), k = tid & 7;
    float ce = 0.f;
    if (e < cnt) {
      int w = list_[e];
      int label = w >> 8, lpos = w & 255;
      int i = i0 + (lpos >> 4), j = j0 + (lpos & 15);
      int pix = i * W_ + j;
      float lzc = logZ[b * HW_ + pix];
      int ic = min(max(i + nx9[k], 0), H_ - 1);
      int jc = min(max(j + ny9[k], 0), W_ - 1);
      int npx = ic * W_ + jc;
      float lzn = logZ[b * HW_ + npx], Sn = S[b * HW_ + npx];
      float dot = 0.f;
      #pragma unroll
      for (int c = 0; c < C_; ++c)
        dot += __expf(bse[c * HW_ + npx] - lzn) * bse[c * HW_ + pix];
      float kv = Sn - dot + lzc;
      float kmax = kv;
      #pragma unroll
      for (int o = 1; o < 8; o <<= 1) kmax = fmaxf(kmax, __shfl_xor(kmax, o));
      float ssum = __expf(kv - kmax);
      #pragma unroll
      for (int o = 1; o < 8; o <<= 1) ssum += __shfl_xor(ssum, o);
      float kll = __shfl(kv, (lane & ~7) | label);
      if (k == 0) ce = kmax + __logf(ssum) - kll;
    }
    acc += ce;
  }
  block_reduce_add_w(acc, out, 4);
}

// ---------------- launch -----------------------------------------------------
extern "C" void kernel_launch(void* const* d_in, const int* in_sizes, int n_in,
                              void* d_out, int out_size, void* d_ws, size_t ws_size,
                              hipStream_t stream) {
  const float* sl  = (const float*)d_in[0];
  const int*   tgt = (const int*)d_in[1];
  float* out = (float*)d_out;

  int*   hist    = (int*)d_ws;                 // 257 ints (zeroed by k_rowdt)
  float* eps_sel = (float*)d_ws + 320;
  float* logZ    = (float*)d_ws + 512;
  float* S       = logZ + NPIX_;
  float* kl_map  = S + NPIX_;
  int*   dist    = (int*)(kl_map + NPIX_);
  int*   Rt      = dist + NPIX_;

  k_rowdt<<<B_ * H_, W_, 0, stream>>>(tgt, Rt, hist, out);
  k_soft<<<NPIX_ / 2 / 256, 256, 0, stream>>>(sl, tgt, logZ, S, kl_map, hist, out);
  k_coldt<<<B_ * W_, H_, 0, stream>>>(Rt, dist, hist, eps_sel);
  k_maskce<<<dim3(W_ / 16, H_ / 16, B_), 256, 0, stream>>>(sl, logZ, S, kl_map, dist, eps_sel, out);
}

// Round 9
// 142.828 us; speedup vs baseline: 1.4143x; 1.0561x over previous
//
#include <hip/hip_runtime.h>
#include <math.h>

#define B_    4
#define C_    19
#define H_    320
#define W_    320
#define HW_   (H_*W_)
#define CHW_  (C_*HW_)
#define NPIX_ (B_*HW_)
#define NEPS_ 256
#define BIGI_ (1<<20)
#define INF_  0x3fffffff
#define IGN_  255

// Compile-time exact replica of the reference eps chain: e0=1e-5f, e_{k+1}=e_k*1.2f
struct EpsTab { float v[NEPS_]; };
static constexpr EpsTab make_eps() {
  EpsTab t{}; float e = 1e-5f;
  for (int k = 0; k < NEPS_; ++k) { t.v[k] = e; e = e * 1.2f; }
  return t;
}
__device__ __constant__ EpsTab EPS = make_eps();

// ---------------- reduction helper (nw full waves) ---------------------------
__device__ __forceinline__ void block_reduce_add_w(float v, float* out, int nw) {
  #pragma unroll
  for (int o = 32; o > 0; o >>= 1) v += __shfl_down(v, o);
  __shared__ float shr[8];
  int lane = threadIdx.x & 63, wid = threadIdx.x >> 6;
  if (lane == 0) shr[wid] = v;
  __syncthreads();
  if (threadIdx.x == 0) {
    float s = 0.f;
    for (int w = 0; w < nw; ++w) s += shr[w];
    atomicAdd(out, s);
  }
}

__device__ __forceinline__ int eps_bin(float kl, const float* et) {
  // #{k : e_k < kl}, log2 guess + exact correction (identical compares to ref)
  if (!(kl > 1e-5f)) return 0;
  int g = (int)((__log2f(kl) + 16.6096404f) * 3.8017840f);
  g = min(max(g, 0), NEPS_ - 1);
  while (g < NEPS_ && et[g] < kl) ++g;
  while (g > 0 && !(et[g - 1] < kl)) --g;
  return g;
}

// ---------------- K1: row distance transform + workspace init ---------------
__global__ __launch_bounds__(320) void k_rowdt(const int* __restrict__ tgt, int* __restrict__ Rt,
                                               int* __restrict__ hist, float* __restrict__ out) {
  int bid = blockIdx.x;                  // b*H_ + i
  int b = bid / H_, i = bid - b * H_;
  int j = threadIdx.x, lane = j & 63, wv = j >> 6;
  if (bid == 0) {
    if (j < 257) hist[j] = 0;
    if (j == 319) out[0] = 0.f;
  }
  bool hd = (i < H_ - 1);
  const int* trow = tgt + b * HW_ + i * W_;
  int t0 = trow[j];
  int t1 = hd ? trow[W_ + j] : t0;
  int t0r = (j < W_ - 1) ? trow[j + 1] : t0;
  bool bnd = (t0 == IGN_) || (t1 != t0) || (t0r != t0);
  int s = bnd ? 0 : BIGI_;
  int a = s - j, c = s + j;
  #pragma unroll
  for (int o = 1; o < 64; o <<= 1) {
    int v = __shfl_up(a, o);
    if (lane >= o) a = min(a, v);
    int w = __shfl_down(c, o);
    if (lane + o < 64) c = min(c, w);
  }
  __shared__ int wa[5], wc[5];
  if (lane == 63) wa[wv] = a;
  if (lane == 0)  wc[wv] = c;
  __syncthreads();
  #pragma unroll
  for (int w = 0; w < 5; ++w) {
    if (w < wv) a = min(a, wa[w]);
    if (w > wv) c = min(c, wc[w]);
  }
  Rt[(b * W_ + j) * H_ + i] = min(a + j, c - j);   // transposed store
}

// ---------------- K0: per-PAIR softmax/KL (float2 + batched prefetch) -------
// EXACT round-6 version (measured best: ~29us; the shfl-right variant was
// +11.6us at full grid -- per-channel shfl serializes against the exp chain).
__global__ __launch_bounds__(256) void k_soft(const float* __restrict__ sl, const int* __restrict__ tgt,
                                              float* __restrict__ logZ, float* __restrict__ S,
                                              float* __restrict__ kl_map, int* __restrict__ hist,
                                              float* __restrict__ out) {
  int t = blockIdx.x * 256 + threadIdx.x;        // pair index, 0..NPIX_/2-1
  int b = t / (HW_ / 2), q = t - b * (HW_ / 2);
  int p = q * 2;                                 // pixel base (j even)
  int i = p / W_, j = p - i * W_;
  bool hd = (i < H_ - 1);
  bool hr1 = (j + 2 < W_);                       // pixel1 has a right neighbor
  __shared__ float et[NEPS_];
  __shared__ int sh[257];
  et[threadIdx.x] = EPS.v[threadIdx.x];
  sh[threadIdx.x] = 0;
  if (threadIdx.x == 0) sh[256] = 0;

  const float* base = sl + (size_t)b * CHW_ + p;
  int2 t2 = *(const int2*)(tgt + b * HW_ + p);

  float se0=0.f,se1=0.f, E0=0.f,E1=0.f;
  float dD0=0.f,dD1=0.f, sB0=0.f,sB1=0.f;
  float dR0=0.f,dR1=0.f, sR1=0.f;
  float xt0=0.f,xt1=0.f;
  #pragma unroll
  for (int c0 = 0; c0 < C_; c0 += 5) {
    const int NB = (c0 + 5 <= C_) ? 5 : (C_ - c0);
    // ---- phase A: issue the whole batch (independent loads) ----
    float2 xo[5], xd[5];
    float  xr[5];
    #pragma unroll
    for (int k = 0; k < NB; ++k) {
      const float* pc = base + (c0 + k) * HW_;
      xo[k] = *(const float2*)pc;
      xd[k] = hd ? *(const float2*)(pc + W_) : make_float2(0.f, 0.f);
      xr[k] = hr1 ? pc[2] : 0.f;
    }
    // ---- phase B: consume in identical c-ascending order ----
    #pragma unroll
    for (int k = 0; k < NB; ++k) {
      int c = c0 + k;
      float e0 = __expf(xo[k].x), e1 = __expf(xo[k].y);
      se0 += e0; E0 += e0 * xo[k].x;
      se1 += e1; E1 += e1 * xo[k].y;
      dD0 += e0 * xd[k].x; dD1 += e1 * xd[k].y;
      sB0 += __expf(xd[k].x); sB1 += __expf(xd[k].y);
      dR0 += e0 * xo[k].y; dR1 += e1 * xr[k];
      sR1 += __expf(xr[k]);
      if (c == t2.x) xt0 = xo[k].x;
      if (c == t2.y) xt1 = xo[k].y;
    }
  }
  float lz0 = __logf(se0), lz1 = __logf(se1);
  float Sv0 = E0 / se0 - lz0, Sv1 = E1 / se1 - lz1;
  float nll = ((t2.x != IGN_) ? (lz0 - xt0) : 0.f) + ((t2.y != IGN_) ? (lz1 - xt1) : 0.f);
  // kl_tb (0 at last row)
  float kl0 = hd ? (Sv0 - dD0 / se0 + __logf(sB0)) : 0.f;
  float kl1 = hd ? (Sv1 - dD1 / se1 + __logf(sB1)) : 0.f;
  // kl_lr: pixel0's right neighbor is pixel1 (register stats, bitwise = its own)
  kl0 += Sv0 - dR0 / se0 + lz1;
  if (hr1) kl1 += Sv1 - dR1 / se1 + __logf(sR1);
  int gp = b * HW_ + p;
  *(float2*)(logZ + gp)   = make_float2(lz0, lz1);
  *(float2*)(S + gp)      = make_float2(Sv0, Sv1);
  *(float2*)(kl_map + gp) = make_float2(kl0, kl1);
  __syncthreads();                       // et/sh init visible
  atomicAdd(&sh[eps_bin(kl0, et)], 1);
  atomicAdd(&sh[eps_bin(kl1, et)], 1);
  __syncthreads();
  if (sh[threadIdx.x]) atomicAdd(&hist[threadIdx.x], sh[threadIdx.x]);
  if (threadIdx.x == 0 && sh[256]) atomicAdd(&hist[256], sh[256]);
  block_reduce_add_w(nll, out, 4);
}

// ---------------- K2: column combine + (block 0) eps selection --------------
__global__ __launch_bounds__(H_) void k_coldt(const int* __restrict__ Rt, int* __restrict__ dist,
                                              const int* __restrict__ hist, float* __restrict__ eps_sel) {
  int b = blockIdx.x / W_, j = blockIdx.x % W_, tid = threadIdx.x;
  __shared__ int lev[9][H_];
  lev[0][tid] = Rt[(b * W_ + j) * H_ + tid];
  int Ri = lev[0][tid];
  for (int l = 1; l <= 8; ++l) {
    int half = 1 << (l - 1);
    __syncthreads();
    int other = (tid + half < H_) ? lev[l - 1][tid + half] : INF_;
    lev[l][tid] = min(lev[l - 1][tid], other);
  }
  __syncthreads();
  int i0 = tid;
  auto feas = [&](int dd) -> bool {
    int lo = max(0, i0 - dd), hi = min(H_ - 1, i0 + dd);
    int len = hi - lo + 1;
    int l = 31 - __clz(len);
    int m = min(lev[l][lo], lev[l][hi - (1 << l) + 1]);
    return m <= dd;
  };
  int d;
  int hi = min(Ri, 512);                 // d <= R[i0]
  if (!feas(hi)) d = B_ + 1 + H_ + W_;   // no seed in image
  else {
    int lo = 0;
    while (lo < hi) { int mid = (lo + hi) >> 1; if (feas(mid)) hi = mid; else lo = mid + 1; }
    d = lo;
  }
  dist[(b * H_ + i0) * W_ + j] = d;
  // block 0: eps via suffix scan of hist (bins 1..256)
  if (blockIdx.x == 0) {
    __shared__ int g[256];
    __shared__ int bestk;
    if (tid < 256) g[tid] = hist[tid + 1];
    if (tid == 0) bestk = NEPS_ - 1;
    __syncthreads();
    #pragma unroll
    for (int ofs = 1; ofs < 256; ofs <<= 1) {
      int v = 0;
      if (tid < 256) v = g[tid] + ((tid + ofs < 256) ? g[tid + ofs] : 0);
      __syncthreads();
      if (tid < 256) g[tid] = v;
      __syncthreads();
    }
    if (tid < 256 && g[tid] <= 5120) atomicMin(&bestk, tid);
    __syncthreads();
    if (tid == 0) eps_sel[0] = EPS.v[bestk];
  }
}

// ---------------- K3: mask+direction+dterm + LDS-staged CE ------------------
// CE phase rebuilt: stage the FULL 18x18 logits halo (19 ch, clamped indices
// = bit-identical to reference edge-padding) + logZ/S halo into LDS, then the
// CE dot reads LDS only. Replaces ~29k scattered 4B global loads per block
// (95 valid entries x 8 lanes x 38 loads, center logits 8x-redundant) with
// ~6.2k coalesced staging loads. Same float values consumed in the same
// c-ascending order -> bitwise unchanged (absmax 0.0 invariant).
// LDS ~31 KB -> ~5 blocks/CU (grid is 6.25/CU).
__global__ __launch_bounds__(256) void k_maskce(const float* __restrict__ sl, const float* __restrict__ logZ,
                                                const float* __restrict__ S, const float* __restrict__ kl_map,
                                                const int* __restrict__ dist, const float* __restrict__ eps_sel,
                                                float* __restrict__ out) {
  const int nx9[9] = {1,-1,0,0,-1,1,-1,1,0};
  const int ny9[9] = {0,0,-1,1,1,1,-1,-1,0};
  int tid = threadIdx.x;
  int b = blockIdx.z;
  int i0 = blockIdx.y * 16, j0 = blockIdx.x * 16;
  float eps = eps_sel[0];
  __shared__ float kt[18][19];
  __shared__ int   dt_[18][19];
  __shared__ float xs[C_][18][18];       // logits halo (clamped)
  __shared__ float lzs[18][18];          // logZ halo (clamped)
  __shared__ float Ss[18][18];           // S halo (clamped)
  for (int e = tid; e < 324; e += 256) {
    int r = e / 18, cc = e - r * 18;
    int gi = i0 - 1 + r, gj = j0 - 1 + cc;
    bool in = (gi >= 0 && gi < H_ && gj >= 0 && gj < W_);
    int gidx = (b * H_ + gi) * W_ + gj;
    kt[r][cc]  = in ? kl_map[gidx] : -1e30f;
    dt_[r][cc] = in ? dist[gidx] : 100000;
    int gic = min(max(gi, 0), H_ - 1), gjc = min(max(gj, 0), W_ - 1);
    int cidx = b * HW_ + gic * W_ + gjc;
    lzs[r][cc] = logZ[cidx];
    Ss[r][cc]  = S[cidx];
  }
  const float* gb = sl + (size_t)b * CHW_;
  for (int idx = tid; idx < C_ * 324; idx += 256) {
    int c = idx / 324, rc = idx - c * 324;
    int r = rc / 18, cc = rc - r * 18;
    int gic = min(max(i0 - 1 + r, 0), H_ - 1);
    int gjc = min(max(j0 - 1 + cc, 0), W_ - 1);
    xs[c][r][cc] = gb[c * HW_ + gic * W_ + gjc];
  }
  __syncthreads();
  int li = tid >> 4, lj = tid & 15;
  bool mask = false;
  #pragma unroll
  for (int dr = 0; dr < 3; ++dr)
    #pragma unroll
    for (int dc = 0; dc < 3; ++dc)
      mask |= (kt[li + dr][lj + dc] > eps);
  int best = INF_, dir = 0;
  #pragma unroll
  for (int k = 0; k < 9; ++k) {
    int r = dt_[li + 1 + nx9[k]][lj + 1 + ny9[k]];
    if (r < best) { best = r; dir = k; }
  }
  bool valid = mask && (dir != 8);
  float acc = valid ? fminf((float)dt_[li + 1][lj + 1], 20.f) * (1.f / 20.f) : 0.f;
  // compact valid pixels into LDS list
  __shared__ int list_[256];
  __shared__ int woff[4];
  __shared__ int tot_s;
  int lane = tid & 63, wid = tid >> 6;
  unsigned long long vote = __ballot(valid);
  if (lane == 0) woff[wid] = __popcll(vote);
  __syncthreads();
  if (tid == 0) {
    int c0 = woff[0], c1 = woff[1], c2 = woff[2], c3 = woff[3];
    tot_s = c0 + c1 + c2 + c3;
    woff[0] = 0; woff[1] = c0; woff[2] = c0 + c1; woff[3] = c0 + c1 + c2;
  }
  __syncthreads();
  if (valid)
    list_[woff[wid] + __popcll(vote & ((1ULL << lane) - 1ULL))] = tid | (min(dir, 7) << 8);
  __syncthreads();
  int cnt = tot_s;
  // CE: 8 lanes per entry (lane k = neighbor k), all operands from LDS
  for (int base0 = 0; base0 < cnt; base0 += 32) {
    int e = base0 + (tid >> 3), k = tid & 7;
    float ce = 0.f;
    if (e < cnt) {
      int w = list_[e];
      int label = w >> 8, lpos = w & 255;
      int pi = (lpos >> 4) + 1, pj = (lpos & 15) + 1;   // center, halo coords
      int ri = pi + nx9[k], rj = pj + ny9[k];           // neighbor, halo coords
      float lzc = lzs[pi][pj];
      float lzn = lzs[ri][rj], Sn = Ss[ri][rj];
      float dot = 0.f;
      #pragma unroll
      for (int c = 0; c < C_; ++c)
        dot += __expf(xs[c][ri][rj] - lzn) * xs[c][pi][pj];
      float kv = Sn - dot + lzc;
      float kmax = kv;
      #pragma unroll
      for (int o = 1; o < 8; o <<= 1) kmax = fmaxf(kmax, __shfl_xor(kmax, o));
      float ssum = __expf(kv - kmax);
      #pragma unroll
      for (int o = 1; o < 8; o <<= 1) ssum += __shfl_xor(ssum, o);
      float kll = __shfl(kv, (lane & ~7) | label);
      if (k == 0) ce = kmax + __logf(ssum) - kll;
    }
    acc += ce;
  }
  block_reduce_add_w(acc, out, 4);
}

// ---------------- launch -----------------------------------------------------
extern "C" void kernel_launch(void* const* d_in, const int* in_sizes, int n_in,
                              void* d_out, int out_size, void* d_ws, size_t ws_size,
                              hipStream_t stream) {
  const float* sl  = (const float*)d_in[0];
  const int*   tgt = (const int*)d_in[1];
  float* out = (float*)d_out;

  int*   hist    = (int*)d_ws;                 // 257 ints (zeroed by k_rowdt)
  float* eps_sel = (float*)d_ws + 320;
  float* logZ    = (float*)d_ws + 512;
  float* S       = logZ + NPIX_;
  float* kl_map  = S + NPIX_;
  int*   dist    = (int*)(kl_map + NPIX_);
  int*   Rt      = dist + NPIX_;

  k_rowdt<<<B_ * H_, W_, 0, stream>>>(tgt, Rt, hist, out);
  k_soft<<<NPIX_ / 2 / 256, 256, 0, stream>>>(sl, tgt, logZ, S, kl_map, hist, out);
  k_coldt<<<B_ * W_, H_, 0, stream>>>(Rt, dist, hist, eps_sel);
  k_maskce<<<dim3(W_ / 16, H_ / 16, B_), 256, 0, stream>>>(sl, logZ, S, kl_map, dist, eps_sel, out);
}

// Round 11
// 140.875 us; speedup vs baseline: 1.4339x; 1.0139x over previous
//
#include <hip/hip_runtime.h>
#include <math.h>

#define B_    4
#define C_    19
#define H_    320
#define W_    320
#define HW_   (H_*W_)
#define CHW_  (C_*HW_)
#define NPIX_ (B_*HW_)
#define NEPS_ 256
#define BIGI_ (1<<20)
#define INF_  0x3fffffff
#define IGN_  255

// Compile-time exact replica of the reference eps chain: e0=1e-5f, e_{k+1}=e_k*1.2f
struct EpsTab { float v[NEPS_]; };
static constexpr EpsTab make_eps() {
  EpsTab t{}; float e = 1e-5f;
  for (int k = 0; k < NEPS_; ++k) { t.v[k] = e; e = e * 1.2f; }
  return t;
}
__device__ __constant__ EpsTab EPS = make_eps();

// ---------------- reduction helper (nw full waves) ---------------------------
__device__ __forceinline__ void block_reduce_add_w(float v, float* out, int nw) {
  #pragma unroll
  for (int o = 32; o > 0; o >>= 1) v += __shfl_down(v, o);
  __shared__ float shr[8];
  int lane = threadIdx.x & 63, wid = threadIdx.x >> 6;
  if (lane == 0) shr[wid] = v;
  __syncthreads();
  if (threadIdx.x == 0) {
    float s = 0.f;
    for (int w = 0; w < nw; ++w) s += shr[w];
    atomicAdd(out, s);
  }
}

__device__ __forceinline__ int eps_bin(float kl, const float* et) {
  // #{k : e_k < kl}, log2 guess + exact correction (identical compares to ref)
  if (!(kl > 1e-5f)) return 0;
  int g = (int)((__log2f(kl) + 16.6096404f) * 3.8017840f);
  g = min(max(g, 0), NEPS_ - 1);
  while (g < NEPS_ && et[g] < kl) ++g;
  while (g > 0 && !(et[g - 1] < kl)) --g;
  return g;
}

// ---------------- K1: row distance transform + workspace init ---------------
__global__ __launch_bounds__(320) void k_rowdt(const int* __restrict__ tgt, int* __restrict__ Rt,
                                               int* __restrict__ hist, float* __restrict__ out) {
  int bid = blockIdx.x;                  // b*H_ + i
  int b = bid / H_, i = bid - b * H_;
  int j = threadIdx.x, lane = j & 63, wv = j >> 6;
  if (bid == 0) {
    if (j < 257) hist[j] = 0;
    if (j == 319) out[0] = 0.f;
  }
  bool hd = (i < H_ - 1);
  const int* trow = tgt + b * HW_ + i * W_;
  int t0 = trow[j];
  int t1 = hd ? trow[W_ + j] : t0;
  int t0r = (j < W_ - 1) ? trow[j + 1] : t0;
  bool bnd = (t0 == IGN_) || (t1 != t0) || (t0r != t0);
  int s = bnd ? 0 : BIGI_;
  int a = s - j, c = s + j;
  #pragma unroll
  for (int o = 1; o < 64; o <<= 1) {
    int v = __shfl_up(a, o);
    if (lane >= o) a = min(a, v);
    int w = __shfl_down(c, o);
    if (lane + o < 64) c = min(c, w);
  }
  __shared__ int wa[5], wc[5];
  if (lane == 63) wa[wv] = a;
  if (lane == 0)  wc[wv] = c;
  __syncthreads();
  #pragma unroll
  for (int w = 0; w < 5; ++w) {
    if (w < wv) a = min(a, wa[w]);
    if (w > wv) c = min(c, wc[w]);
  }
  Rt[(b * W_ + j) * H_ + i] = min(a + j, c - j);   // transposed store
}

// ---------------- K0: per-PAIR softmax/KL + 8-dir CE partials ---------------
// R6 f2b structure (all original accumulations bitwise-unchanged), PLUS a
// second channel loop computing the 8 directed-KL partials per pixel:
//   PK[p][k] = S_p - sum_c expf(x_p[c]-lz_p)*x_{clamp(p+dir_k)}[c]
// -- exactly the (Sn - dot) of the old k_maskce CE (same expf args, same
// c-ascending FMA order); clamped row pointers / col addresses reproduce the
// reference's edge padding natively. Stored coalesced as [NPIX][8] (2 float4
// per pixel). k_maskce then never touches slices again (its 37 MB re-fetch,
// the measured 38us, collapses to ~18 MB of PK/halo reads).
__global__ __launch_bounds__(256) void k_soft(const float* __restrict__ sl, const int* __restrict__ tgt,
                                              float* __restrict__ logZ, float* __restrict__ kl_map,
                                              float* __restrict__ PK, int* __restrict__ hist,
                                              float* __restrict__ out) {
  int t = blockIdx.x * 256 + threadIdx.x;        // pair index, 0..NPIX_/2-1
  int b = t / (HW_ / 2), q = t - b * (HW_ / 2);
  int p = q * 2;                                 // pixel base (j even)
  int i = p / W_, j = p - i * W_;
  bool hd = (i < H_ - 1);
  bool hr1 = (j + 2 < W_);                       // pixel1 has a right neighbor
  __shared__ float et[NEPS_];
  __shared__ int sh[257];
  et[threadIdx.x] = EPS.v[threadIdx.x];
  sh[threadIdx.x] = 0;
  if (threadIdx.x == 0) sh[256] = 0;

  const float* base = sl + (size_t)b * CHW_ + p;
  int2 t2 = *(const int2*)(tgt + b * HW_ + p);

  float x0s[C_], x1s[C_];                        // own logits stash (static idx)
  float se0=0.f,se1=0.f, E0=0.f,E1=0.f;
  float dD0=0.f,dD1=0.f, sB0=0.f,sB1=0.f;
  float dR0=0.f,dR1=0.f, sR1=0.f;
  float xt0=0.f,xt1=0.f;
  #pragma unroll
  for (int c0 = 0; c0 < C_; c0 += 5) {
    const int NB = (c0 + 5 <= C_) ? 5 : (C_ - c0);
    float2 xo[5], xd[5];
    float  xr[5];
    #pragma unroll
    for (int k = 0; k < NB; ++k) {
      const float* pc = base + (c0 + k) * HW_;
      xo[k] = *(const float2*)pc;
      xd[k] = hd ? *(const float2*)(pc + W_) : make_float2(0.f, 0.f);
      xr[k] = hr1 ? pc[2] : 0.f;
    }
    #pragma unroll
    for (int k = 0; k < NB; ++k) {
      int c = c0 + k;
      x0s[c] = xo[k].x; x1s[c] = xo[k].y;
      float e0 = __expf(xo[k].x), e1 = __expf(xo[k].y);
      se0 += e0; E0 += e0 * xo[k].x;
      se1 += e1; E1 += e1 * xo[k].y;
      dD0 += e0 * xd[k].x; dD1 += e1 * xd[k].y;
      sB0 += __expf(xd[k].x); sB1 += __expf(xd[k].y);
      dR0 += e0 * xo[k].y; dR1 += e1 * xr[k];
      sR1 += __expf(xr[k]);
      if (c == t2.x) xt0 = xo[k].x;
      if (c == t2.y) xt1 = xo[k].y;
    }
  }
  float lz0 = __logf(se0), lz1 = __logf(se1);
  float Sv0 = E0 / se0 - lz0, Sv1 = E1 / se1 - lz1;
  float nll = ((t2.x != IGN_) ? (lz0 - xt0) : 0.f) + ((t2.y != IGN_) ? (lz1 - xt1) : 0.f);
  float kl0 = hd ? (Sv0 - dD0 / se0 + __logf(sB0)) : 0.f;
  float kl1 = hd ? (Sv1 - dD1 / se1 + __logf(sB1)) : 0.f;
  kl0 += Sv0 - dR0 / se0 + lz1;
  if (hr1) kl1 += Sv1 - dR1 / se1 + __logf(sR1);

  // ---- loop 2: 8-direction CE dot partials (clamped neighborhood) ----
  // dir order k0..k7 = (1,0)(-1,0)(0,-1)(0,1)(-1,1)(1,1)(-1,-1)(1,-1)
  {
    const float* gb = sl + (size_t)b * CHW_;
    int rU = (i > 0) ? i - 1 : 0;
    int rD = (i < H_ - 1) ? i + 1 : i;
    int jL = (j > 0) ? j - 1 : 0;
    int jR = (j + 2 < W_) ? j + 2 : W_ - 1;
    const float* pu = gb + rU * W_;
    const float* pd = gb + rD * W_;
    const float* pm = gb + i * W_;
    float A00=0.f,A01=0.f,A02=0.f,A03=0.f,A04=0.f,A05=0.f,A06=0.f,A07=0.f;
    float A10=0.f,A11=0.f,A12=0.f,A13=0.f,A14=0.f,A15=0.f,A16=0.f,A17=0.f;
    #pragma unroll
    for (int c = 0; c < C_; ++c) {
      size_t o = (size_t)c * HW_;
      float2 u2 = *(const float2*)(pu + o + j);
      float uL = pu[o + jL], uR = pu[o + jR];
      float2 d2 = *(const float2*)(pd + o + j);
      float dL = pd[o + jL], dRv = pd[o + jR];
      float mL = pm[o + jL], mR = pm[o + jR];
      float ec0 = __expf(x0s[c] - lz0);
      float ec1 = __expf(x1s[c] - lz1);
      A00 += ec0 * d2.x;   A01 += ec0 * u2.x;   A02 += ec0 * mL;     A03 += ec0 * x1s[c];
      A04 += ec0 * u2.y;   A05 += ec0 * d2.y;   A06 += ec0 * uL;     A07 += ec0 * dL;
      A10 += ec1 * d2.y;   A11 += ec1 * u2.y;   A12 += ec1 * x0s[c]; A13 += ec1 * mR;
      A14 += ec1 * uR;     A15 += ec1 * dRv;    A16 += ec1 * u2.x;   A17 += ec1 * d2.x;
    }
    int gp = b * HW_ + p;
    float* pk0 = PK + ((size_t)gp << 3);
    *(float4*)(pk0)     = make_float4(Sv0 - A00, Sv0 - A01, Sv0 - A02, Sv0 - A03);
    *(float4*)(pk0 + 4) = make_float4(Sv0 - A04, Sv0 - A05, Sv0 - A06, Sv0 - A07);
    *(float4*)(pk0 + 8) = make_float4(Sv1 - A10, Sv1 - A11, Sv1 - A12, Sv1 - A13);
    *(float4*)(pk0 + 12)= make_float4(Sv1 - A14, Sv1 - A15, Sv1 - A16, Sv1 - A17);
  }

  int gp = b * HW_ + p;
  *(float2*)(logZ + gp)   = make_float2(lz0, lz1);
  *(float2*)(kl_map + gp) = make_float2(kl0, kl1);
  __syncthreads();                       // et/sh init visible
  atomicAdd(&sh[eps_bin(kl0, et)], 1);
  atomicAdd(&sh[eps_bin(kl1, et)], 1);
  __syncthreads();
  if (sh[threadIdx.x]) atomicAdd(&hist[threadIdx.x], sh[threadIdx.x]);
  if (threadIdx.x == 0 && sh[256]) atomicAdd(&hist[256], sh[256]);
  block_reduce_add_w(nll, out, 4);
}

// ---------------- K2: column combine + (block 0) eps selection --------------
__global__ __launch_bounds__(H_) void k_coldt(const int* __restrict__ Rt, int* __restrict__ dist,
                                              const int* __restrict__ hist, float* __restrict__ eps_sel) {
  int b = blockIdx.x / W_, j = blockIdx.x % W_, tid = threadIdx.x;
  __shared__ int lev[9][H_];
  lev[0][tid] = Rt[(b * W_ + j) * H_ + tid];
  int Ri = lev[0][tid];
  for (int l = 1; l <= 8; ++l) {
    int half = 1 << (l - 1);
    __syncthreads();
    int other = (tid + half < H_) ? lev[l - 1][tid + half] : INF_;
    lev[l][tid] = min(lev[l - 1][tid], other);
  }
  __syncthreads();
  int i0 = tid;
  auto feas = [&](int dd) -> bool {
    int lo = max(0, i0 - dd), hi = min(H_ - 1, i0 + dd);
    int len = hi - lo + 1;
    int l = 31 - __clz(len);
    int m = min(lev[l][lo], lev[l][hi - (1 << l) + 1]);
    return m <= dd;
  };
  int d;
  int hi = min(Ri, 512);                 // d <= R[i0]
  if (!feas(hi)) d = B_ + 1 + H_ + W_;   // no seed in image
  else {
    int lo = 0;
    while (lo < hi) { int mid = (lo + hi) >> 1; if (feas(mid)) hi = mid; else lo = mid + 1; }
    d = lo;
  }
  dist[(b * H_ + i0) * W_ + j] = d;
  // block 0: eps via suffix scan of hist (bins 1..256)
  if (blockIdx.x == 0) {
    __shared__ int g[256];
    __shared__ int bestk;
    if (tid < 256) g[tid] = hist[tid + 1];
    if (tid == 0) bestk = NEPS_ - 1;
    __syncthreads();
    #pragma unroll
    for (int ofs = 1; ofs < 256; ofs <<= 1) {
      int v = 0;
      if (tid < 256) v = g[tid] + ((tid + ofs < 256) ? g[tid + ofs] : 0);
      __syncthreads();
      if (tid < 256) g[tid] = v;
      __syncthreads();
    }
    if (tid < 256 && g[tid] <= 5120) atomicMin(&bestk, tid);
    __syncthreads();
    if (tid == 0) eps_sel[0] = EPS.v[bestk];
  }
}

// ---------------- K3: mask+direction+dterm + CE from precomputed partials ---
// No slices access. Per valid pixel: 8 local PK reads + logZ; kv[k] =
// PK[src][d] + lz_center where src = clamp(p+dir_k), d = direction src->p
// (opp(k) interior; select formula at borders -- clamped loads in k_soft make
// collapsed slots hold exactly the old clamped-dot values). Max/sum trees
// replicate the old shfl_xor pairing bitwise. No compaction needed.
__global__ __launch_bounds__(256) void k_maskce(const float* __restrict__ PK, const float* __restrict__ logZ,
                                                const float* __restrict__ kl_map, const int* __restrict__ dist,
                                                const float* __restrict__ eps_sel, float* __restrict__ out) {
  const int nx9[9] = {1,-1,0,0,-1,1,-1,1,0};
  const int ny9[9] = {0,0,-1,1,1,1,-1,-1,0};
  int tid = threadIdx.x;
  int b = blockIdx.z;
  int i0 = blockIdx.y * 16, j0 = blockIdx.x * 16;
  float eps = eps_sel[0];
  __shared__ float kt[18][19];
  __shared__ int   dt_[18][19];
  for (int e = tid; e < 324; e += 256) {
    int r = e / 18, cc = e - r * 18;
    int gi = i0 - 1 + r, gj = j0 - 1 + cc;
    bool in = (gi >= 0 && gi < H_ && gj >= 0 && gj < W_);
    int gidx = (b * H_ + gi) * W_ + gj;
    kt[r][cc]  = in ? kl_map[gidx] : -1e30f;
    dt_[r][cc] = in ? dist[gidx] : 100000;
  }
  __syncthreads();
  int li = tid >> 4, lj = tid & 15;
  bool mask = false;
  #pragma unroll
  for (int dr = 0; dr < 3; ++dr)
    #pragma unroll
    for (int dc = 0; dc < 3; ++dc)
      mask |= (kt[li + dr][lj + dc] > eps);
  int best = INF_, dir = 0;
  #pragma unroll
  for (int k = 0; k < 9; ++k) {
    int r = dt_[li + 1 + nx9[k]][lj + 1 + ny9[k]];
    if (r < best) { best = r; dir = k; }
  }
  bool valid = mask && (dir != 8);
  float acc = 0.f;
  if (valid) {
    int i = i0 + li, j = j0 + lj;
    acc = fminf((float)dt_[li + 1][lj + 1], 20.f) * (1.f / 20.f);
    int label = min(dir, 7);
    float lzc = logZ[b * HW_ + i * W_ + j];
    float kv0, kv1, kv2, kv3, kv4, kv5, kv6, kv7;
#define SLOT(NX, NY, KV) { \
    int ni = i + (NX); ni = ni < 0 ? 0 : (ni > H_ - 1 ? H_ - 1 : ni); \
    int nj = j + (NY); nj = nj < 0 ? 0 : (nj > W_ - 1 ? W_ - 1 : nj); \
    int di = i - ni, dj = j - nj; \
    int d; \
    if (di == 0 && dj == 0) d = (i == 0) ? 1 : ((i == H_ - 1) ? 0 : ((j == 0) ? 2 : 3)); \
    else if (di == 1)  d = (dj == 0) ? 0 : ((dj == 1) ? 5 : 7); \
    else if (di == -1) d = (dj == 0) ? 1 : ((dj == 1) ? 4 : 6); \
    else               d = (dj == 1) ? 3 : 2; \
    KV = PK[((size_t)(b * HW_ + ni * W_ + nj) << 3) + d] + lzc; }
    SLOT( 1,  0, kv0); SLOT(-1,  0, kv1); SLOT( 0, -1, kv2); SLOT( 0,  1, kv3);
    SLOT(-1,  1, kv4); SLOT( 1,  1, kv5); SLOT(-1, -1, kv6); SLOT( 1, -1, kv7);
#undef SLOT
    // max tree: same pairing as old shfl_xor(1,2,4)
    float kmax = fmaxf(fmaxf(fmaxf(kv0, kv1), fmaxf(kv2, kv3)),
                       fmaxf(fmaxf(kv4, kv5), fmaxf(kv6, kv7)));
    float s01 = __expf(kv0 - kmax) + __expf(kv1 - kmax);
    float s23 = __expf(kv2 - kmax) + __expf(kv3 - kmax);
    float s45 = __expf(kv4 - kmax) + __expf(kv5 - kmax);
    float s67 = __expf(kv6 - kmax) + __expf(kv7 - kmax);
    float ssum = (s01 + s23) + (s45 + s67);
    float kll = label == 0 ? kv0 : label == 1 ? kv1 : label == 2 ? kv2 : label == 3 ? kv3
              : label == 4 ? kv4 : label == 5 ? kv5 : label == 6 ? kv6 : kv7;
    acc += kmax + __logf(ssum) - kll;
  }
  block_reduce_add_w(acc, out, 4);
}

// ---------------- launch -----------------------------------------------------
extern "C" void kernel_launch(void* const* d_in, const int* in_sizes, int n_in,
                              void* d_out, int out_size, void* d_ws, size_t ws_size,
                              hipStream_t stream) {
  const float* sl  = (const float*)d_in[0];
  const int*   tgt = (const int*)d_in[1];
  float* out = (float*)d_out;

  int*   hist    = (int*)d_ws;                 // 257 ints (zeroed by k_rowdt)
  float* eps_sel = (float*)d_ws + 320;
  float* logZ    = (float*)d_ws + 512;
  float* kl_map  = logZ + NPIX_;
  int*   dist    = (int*)(kl_map + NPIX_);
  int*   Rt      = dist + NPIX_;
  float* PK      = (float*)(Rt + NPIX_);       // [NPIX][8] CE partials

  k_rowdt<<<B_ * H_, W_, 0, stream>>>(tgt, Rt, hist, out);
  k_soft<<<NPIX_ / 2 / 256, 256, 0, stream>>>(sl, tgt, logZ, kl_map, PK, hist, out);
  k_coldt<<<B_ * W_, H_, 0, stream>>>(Rt, dist, hist, eps_sel);
  k_maskce<<<dim3(W_ / 16, H_ / 16, B_), 256, 0, stream>>>(PK, logZ, kl_map, dist, eps_sel, out);
}